// Round 1
// baseline (1513.699 us; speedup 1.0000x reference)
//
#include <hip/hip_runtime.h>
#include <math.h>

// ---------------------------------------------------------------------------
// TreeEnergyLoss on MI355X.
// Pipeline: softmax -> 4x (unique-MST forest via Boruvka under (dist, edge-idx)
// total order == reference's stable-sort Kruskal) -> two-pass tree filter ->
// ROI-masked L1 loss.  All per-(forest,batch) work runs in one workgroup with
// the whole problem resident in LDS.
// ---------------------------------------------------------------------------

#define HH 48
#define WW 48
#define NN (HH*WW)          // 2304 nodes
#define EHH (HH*(WW-1))     // 2256 horizontal edges
#define EEE (2*EHH)         // 4512 edges
#define BB 8
#define KK 4
#define TPB 256

// per-problem structure record in ws (ints): parent | wgt | order | levelStart | depth
#define SSTRIDE_W (4*NN+8)
#define P_OFF 0
#define W_OFF NN
#define O_OFF (2*NN)
#define L_OFF (3*NN)
#define D_OFF (4*NN+2)

struct Tap { int o00,o01,o10,o11; float w00,w01,w10,w11; };

__device__ __forceinline__ Tap mk_tap(int r,int c,int sh,int sw){
  float sy=(float)sh/48.0f, sx=(float)sw/48.0f;          // exact (pow2 ratios)
  float ys=fmaxf(((float)r+0.5f)*sy-0.5f,0.0f);
  float xs=fmaxf(((float)c+0.5f)*sx-0.5f,0.0f);
  int y0=(int)ys; if(y0>sh-1) y0=sh-1;
  int x0=(int)xs; if(x0>sw-1) x0=sw-1;
  int y1=y0+1; if(y1>sh-1) y1=sh-1;
  int x1=x0+1; if(x1>sw-1) x1=sw-1;
  float wy=ys-(float)y0, wx=xs-(float)x0;
  Tap t;
  t.o00=y0*sw+x0; t.o01=y0*sw+x1; t.o10=y1*sw+x0; t.o11=y1*sw+x1;
  t.w00=(1.0f-wy)*(1.0f-wx); t.w01=(1.0f-wy)*wx;
  t.w10=wy*(1.0f-wx);        t.w11=wy*wx;
  return t;
}

__device__ __forceinline__ float tap_val(const float* __restrict__ p, const Tap& t){
  return t.w00*p[t.o00]+t.w01*p[t.o01]+t.w10*p[t.o10]+t.w11*p[t.o11];
}

// numpy edge order: horizontal (row-major) first, then vertical.
__device__ __forceinline__ void edge_uv(int e,int& u,int& v){
  if(e<EHH){ int r=e/(WW-1); int c=e-r*(WW-1); u=r*WW+c; v=u+1; }
  else     { int t=e-EHH; u=t; v=t+WW; }
}

// ---------------------------------------------------------------------------
__global__ __launch_bounds__(TPB) void k_prob(const float* __restrict__ preds,
                                              float* __restrict__ probf){
  int t=blockIdx.x*TPB+threadIdx.x;
  if(t>=BB*NN) return;
  int b=t/NN, i=t-b*NN;
  const float* p=preds+(size_t)b*KK*NN+i;
  float x0=p[0],x1=p[NN],x2=p[2*NN],x3=p[3*NN];
  float mx=fmaxf(fmaxf(x0,x1),fmaxf(x2,x3));
  float e0=expf(x0-mx),e1=expf(x1-mx),e2=expf(x2-mx),e3=expf(x3-mx);
  float s=((e0+e1)+(e2+e3));
  float* q=probf+(size_t)b*KK*NN+i;
  q[0]=e0/s; q[NN]=e1/s; q[2*NN]=e2/s; q[3*NN]=e3/s;
}

// ---------------------------------------------------------------------------
// One workgroup per (forest,batch).  ~114 KB LDS.
__global__ __launch_bounds__(TPB) void k_structure(
  const float* __restrict__ lowf, const float* __restrict__ hf1,
  const float* __restrict__ hf2, const float* __restrict__ hf3,
  int* __restrict__ sbase)
{
  __shared__ double dkey[EEE];                  // 36096 B (reused for scan)
  __shared__ unsigned long long bestd[NN];      // 18432 B
  __shared__ int comp[NN];
  __shared__ int lnk[NN];
  __shared__ int beste[NN];
  __shared__ int level[NN];
  __shared__ int parentN[NN];
  __shared__ int hist[NN+2];
  __shared__ unsigned char mstf[EEE];
  __shared__ int flags[4];

  const int tid=threadIdx.x;
  const int pidx=blockIdx.x;
  const int f=pidx>>3, b=pidx&7;
  const float* src; int sh,C; float sigma;
  if(f==0){src=lowf; sh=192; C=3;   sigma=0.02f;}
  else if(f==1){src=hf1; sh=24; C=512; sigma=1.0f;}
  else if(f==2){src=hf2; sh=12; C=512; sigma=1.0f;}
  else        {src=hf3; sh=6;  C=512; sigma=1.0f;}
  const int shw=sh*sh;
  const float* srcb=src+(size_t)b*C*shw;

  int* sp=sbase+(size_t)pidx*SSTRIDE_W;
  int* g_parent=sp+P_OFF;
  float* g_wgt=(float*)(sp+W_OFF);
  int* g_order=sp+O_OFF;
  int* g_ls=sp+L_OFF;

  // ---- edge distances: float64, fixed 4-way partial-sum order (tie-consistent)
  for(int e=tid;e<EEE;e+=TPB){
    int u,v; edge_uv(e,u,v);
    Tap tu=mk_tap(u/WW,u%WW,sh,sh);
    Tap tv=mk_tap(v/WW,v%WW,sh,sh);
    const float* pl=srcb;
    double a0=0,a1=0,a2=0,a3=0; int c=0;
    for(;c+4<=C;c+=4,pl+=4*shw){
      double d0=(double)tap_val(pl,tu)      -(double)tap_val(pl,tv);
      double d1=(double)tap_val(pl+shw,tu)  -(double)tap_val(pl+shw,tv);
      double d2=(double)tap_val(pl+2*shw,tu)-(double)tap_val(pl+2*shw,tv);
      double d3=(double)tap_val(pl+3*shw,tu)-(double)tap_val(pl+3*shw,tv);
      a0+=d0*d0; a1+=d1*d1; a2+=d2*d2; a3+=d3*d3;
    }
    for(;c<C;++c,pl+=shw){
      double d=(double)tap_val(pl,tu)-(double)tap_val(pl,tv);
      a0+=d*d;
    }
    dkey[e]=((a0+a1)+(a2+a3));
  }
  for(int i=tid;i<NN;i+=TPB) comp[i]=i;
  for(int e=tid;e<EEE;e+=TPB) mstf[e]=0;
  __syncthreads();

  // ---- Boruvka: unique MST under strict (dist_bits, edge_index) order ----
  for(int round=0;round<24;++round){
    for(int i=tid;i<NN;i+=TPB){ bestd[i]=~0ull; beste[i]=0x7fffffff; lnk[i]=i; }
    __syncthreads();
    for(int e=tid;e<EEE;e+=TPB){
      int u,v; edge_uv(e,u,v);
      int cu=comp[u], cv=comp[v];
      if(cu!=cv){
        unsigned long long db=(unsigned long long)__double_as_longlong(dkey[e]);
        atomicMin(&bestd[cu],db);
        atomicMin(&bestd[cv],db);
      }
    }
    __syncthreads();
    for(int e=tid;e<EEE;e+=TPB){
      int u,v; edge_uv(e,u,v);
      int cu=comp[u], cv=comp[v];
      if(cu!=cv){
        unsigned long long db=(unsigned long long)__double_as_longlong(dkey[e]);
        if(db==bestd[cu]) atomicMin(&beste[cu],e);
        if(db==bestd[cv]) atomicMin(&beste[cv],e);
      }
    }
    __syncthreads();
    // hook (mutual pair resolved toward smaller id; only 2-cycles possible,
    // and only via the SAME edge since the order is strict)
    for(int i=tid;i<NN;i+=TPB){
      if(comp[i]==i && beste[i]!=0x7fffffff){
        int e=beste[i]; int u,v; edge_uv(e,u,v);
        int cu=comp[u], cv=comp[v];
        int other=(cu==i)?cv:cu;
        bool mutual=(beste[other]==e);
        if(!mutual || other<i){ lnk[i]=other; mstf[e]=1; }
      }
    }
    __syncthreads();
    // pointer jumping to full compression
    for(;;){
      if(tid==0) flags[0]=0;
      __syncthreads();
      for(int i=tid;i<NN;i+=TPB){
        int a=lnk[i]; int a2=lnk[a];
        if(a!=a2){ lnk[i]=a2; flags[0]=1; }
      }
      __syncthreads();
      int done=flags[0];
      __syncthreads();
      if(!done) break;
    }
    for(int i=tid;i<NN;i+=TPB) comp[i]=lnk[comp[i]];
    __syncthreads();
    if(tid==0) flags[1]=0;
    __syncthreads();
    for(int i=tid;i<NN;i+=TPB) if(comp[i]==i) atomicAdd(&flags[1],1);
    __syncthreads();
    int nc=flags[1];
    __syncthreads();
    if(nc<=1) break;
  }

  // ---- BFS from node 0 (tree => parent/level unique, no write races) ----
  for(int i=tid;i<NN;i+=TPB) level[i]=-1;
  __syncthreads();
  if(tid==0){ level[0]=0; parentN[0]=0; }
  __syncthreads();
  int depth=0;
  for(int cur=0;;++cur){
    if(tid==0) flags[2]=0;
    __syncthreads();
    for(int i=tid;i<NN;i+=TPB){
      if(level[i]==cur){
        int r=i/WW, c=i-r*WW;
        if(c>0    && mstf[r*(WW-1)+c-1]   && level[i-1]<0) { level[i-1]=cur+1;  parentN[i-1]=i;  flags[2]=1; }
        if(c<WW-1 && mstf[r*(WW-1)+c]     && level[i+1]<0) { level[i+1]=cur+1;  parentN[i+1]=i;  flags[2]=1; }
        if(r>0    && mstf[EHH+(r-1)*WW+c] && level[i-WW]<0){ level[i-WW]=cur+1; parentN[i-WW]=i; flags[2]=1; }
        if(r<HH-1 && mstf[EHH+r*WW+c]     && level[i+WW]<0){ level[i+WW]=cur+1; parentN[i+WW]=i; flags[2]=1; }
      }
    }
    __syncthreads();
    int any=flags[2];
    __syncthreads();
    if(!any){ depth=cur; break; }
  }

  // ---- wgt[i] = exp(-dist(i,parent)/sigma), reusing the MST edge distance ----
  for(int i=tid;i<NN;i+=TPB){
    int p=parentN[i];
    int r=i/WW, c=i-r*WW;
    int e=-1;
    if(p==i+1)      e=r*(WW-1)+c;
    else if(p==i-1) e=r*(WW-1)+(c-1);
    else if(p==i+WW)e=EHH+i;
    else if(p==i-WW)e=EHH+p;
    g_wgt[i]=(e<0)?1.0f:expf(-(float)dkey[e]/sigma);
    g_parent[i]=p;
  }
  __syncthreads();   // dkey reads done; region reused for scan below

  // ---- counting sort of nodes by level -> order[], levelStart[] ----
  for(int i=tid;i<NN+2;i+=TPB) hist[i]=0;
  __syncthreads();
  for(int i=tid;i<NN;i+=TPB) atomicAdd(&hist[level[i]+1],1);
  __syncthreads();
  int m=depth+2;
  int* scanA=(int*)dkey;
  int* scanB=scanA+(NN+2);
  for(int i=tid;i<m;i+=TPB) scanA[i]=hist[i];
  __syncthreads();
  int* sA=scanA; int* sB=scanB;
  for(int off=1;off<m;off<<=1){
    for(int i=tid;i<m;i+=TPB) sB[i]=sA[i]+((i>=off)?sA[i-off]:0);
    __syncthreads();
    int* tmp=sA; sA=sB; sB=tmp;
  }
  for(int i=tid;i<m;i+=TPB){ g_ls[i]=sA[i]; hist[i]=sA[i]; }
  __syncthreads();
  for(int i=tid;i<NN;i+=TPB){
    int pos=atomicAdd(&hist[level[i]],1);
    g_order[pos]=i;
  }
  if(tid==0) sp[D_OFF]=depth;
}

// ---------------------------------------------------------------------------
// Tree filter, forest 0 (input: softmax probs; output: AS).  In-place LDS A.
__global__ __launch_bounds__(TPB) void k_filter0(
  const float* __restrict__ probf, const int* __restrict__ sbase,
  float* __restrict__ AS)
{
  __shared__ float A[(KK+1)*NN];
  __shared__ float wgtS[NN];
  __shared__ int parS[NN];
  __shared__ int ordS[NN];
  __shared__ int lsS[NN+2];
  const int tid=threadIdx.x;
  const int b=blockIdx.x;
  const int* sp=sbase+(size_t)b*SSTRIDE_W;
  const float* g_wgt=(const float*)(sp+W_OFF);
  const int D=sp[D_OFF];
  for(int t=tid;t<(KK+1)*NN;t+=TPB) A[t]=(t<KK*NN)? probf[(size_t)b*KK*NN+t] : 1.0f;
  for(int i=tid;i<NN;i+=TPB){ wgtS[i]=g_wgt[i]; parS[i]=sp[P_OFF+i]; ordS[i]=sp[O_OFF+i]; }
  for(int i=tid;i<D+2;i+=TPB) lsS[i]=sp[L_OFF+i];
  __syncthreads();
  // upward (leaf->root)
  for(int l=D;l>=1;--l){
    int s=lsS[l], e2=lsS[l+1];
    for(int k=s+tid;k<e2;k+=TPB){
      int i=ordS[k]; int p=parS[i]; float w=wgtS[i];
      #pragma unroll
      for(int c=0;c<=KK;c++) atomicAdd(&A[c*NN+p], w*A[c*NN+i]);
    }
    __syncthreads();
  }
  // downward (root->leaf), in place: parent slot already holds F, own holds A
  for(int l=1;l<=D;++l){
    int s=lsS[l], e2=lsS[l+1];
    for(int k=s+tid;k<e2;k+=TPB){
      int i=ordS[k]; int p=parS[i]; float w=wgtS[i];
      #pragma unroll
      for(int c=0;c<=KK;c++){
        float a=A[c*NN+i];
        A[c*NN+i]=a+w*(A[c*NN+p]-w*a);
      }
    }
    __syncthreads();
  }
  for(int t=tid;t<KK*NN;t+=TPB){
    int c=t/NN, i=t-c*NN;
    AS[(size_t)b*KK*NN+t]=A[c*NN+i]/A[KK*NN+i];
  }
}

// ---------------------------------------------------------------------------
// Tree filter, forests 1..3 (input: AS) + ROI-masked L1 partial loss.
__global__ __launch_bounds__(TPB) void k_filter123(
  const float* __restrict__ AS, const float* __restrict__ probf,
  const float* __restrict__ rois, const int* __restrict__ sbase,
  float* __restrict__ partials)
{
  __shared__ float A[(KK+1)*NN];
  __shared__ float wgtS[NN];
  __shared__ int parS[NN];
  __shared__ int ordS[NN];
  __shared__ int lsS[NN+2];
  __shared__ float red[TPB];
  const int tid=threadIdx.x;
  const int fm1=blockIdx.x/BB, b=blockIdx.x%BB;
  const int pidx=(fm1+1)*BB+b;
  const int* sp=sbase+(size_t)pidx*SSTRIDE_W;
  const float* g_wgt=(const float*)(sp+W_OFF);
  const int D=sp[D_OFF];
  for(int t=tid;t<(KK+1)*NN;t+=TPB) A[t]=(t<KK*NN)? AS[(size_t)b*KK*NN+t] : 1.0f;
  for(int i=tid;i<NN;i+=TPB){ wgtS[i]=g_wgt[i]; parS[i]=sp[P_OFF+i]; ordS[i]=sp[O_OFF+i]; }
  for(int i=tid;i<D+2;i+=TPB) lsS[i]=sp[L_OFF+i];
  __syncthreads();
  for(int l=D;l>=1;--l){
    int s=lsS[l], e2=lsS[l+1];
    for(int k=s+tid;k<e2;k+=TPB){
      int i=ordS[k]; int p=parS[i]; float w=wgtS[i];
      #pragma unroll
      for(int c=0;c<=KK;c++) atomicAdd(&A[c*NN+p], w*A[c*NN+i]);
    }
    __syncthreads();
  }
  for(int l=1;l<=D;++l){
    int s=lsS[l], e2=lsS[l+1];
    for(int k=s+tid;k<e2;k+=TPB){
      int i=ordS[k]; int p=parS[i]; float w=wgtS[i];
      #pragma unroll
      for(int c=0;c<=KK;c++){
        float a=A[c*NN+i];
        A[c*NN+i]=a+w*(A[c*NN+p]-w*a);
      }
    }
    __syncthreads();
  }
  // ROI-masked L1 vs original probs
  float part=0.0f;
  for(int i=tid;i<NN;i+=TPB){
    int r=i/WW, c2=i-r*WW;
    float roi=rois[(size_t)b*(192*192)+(4*r)*192+(4*c2)];
    float den=A[KK*NN+i];
    float s=0.0f;
    #pragma unroll
    for(int c=0;c<KK;c++){
      float ask=A[c*NN+i]/den;
      s+=fabsf(probf[(size_t)b*KK*NN+c*NN+i]-ask);
    }
    part+=roi*s;
  }
  red[tid]=part; __syncthreads();
  for(int s2=TPB/2;s2>0;s2>>=1){ if(tid<s2) red[tid]+=red[tid+s2]; __syncthreads(); }
  if(tid==0) partials[blockIdx.x]=red[0];
}

// ---------------------------------------------------------------------------
__global__ __launch_bounds__(TPB) void k_final(const float* __restrict__ rois,
    const float* __restrict__ partials, const float* __restrict__ wt,
    float* __restrict__ out)
{
  __shared__ float red[TPB];
  const int tid=threadIdx.x;
  float n=0.0f;
  for(int t=tid;t<BB*NN;t+=TPB){
    int b=t/NN, i=t-b*NN; int r=i/WW, c=i-r*WW;
    n += rois[(size_t)b*(192*192)+(4*r)*192+(4*c)];
  }
  red[tid]=n; __syncthreads();
  for(int s=TPB/2;s>0;s>>=1){ if(tid<s) red[tid]+=red[tid+s]; __syncthreads(); }
  if(tid==0){
    float loss=0.0f;
    for(int j=0;j<3*BB;j++) loss+=partials[j];
    float N=red[0];
    out[0]=wt[0]*((N>0.0f)?(loss/N):loss);
  }
}

// ---------------------------------------------------------------------------
extern "C" void kernel_launch(void* const* d_in, const int* in_sizes, int n_in,
                              void* d_out, int out_size, void* d_ws, size_t ws_size,
                              hipStream_t stream) {
  (void)in_sizes; (void)n_in; (void)out_size; (void)ws_size;
  const float* preds=(const float*)d_in[0];
  const float* lowf =(const float*)d_in[1];
  const float* hf1  =(const float*)d_in[2];
  const float* hf2  =(const float*)d_in[3];
  const float* hf3  =(const float*)d_in[4];
  const float* rois =(const float*)d_in[5];
  const float* wt   =(const float*)d_in[6];
  float* out=(float*)d_out;

  char* ws=(char*)d_ws;
  float* partials=(float*)ws;                                   // 24 floats
  float* probf=(float*)(ws+256);                                // B*K*NN
  float* AS   =(float*)(ws+256+(size_t)BB*KK*NN*4);             // B*K*NN
  int*   sbase=(int*)  (ws+256+(size_t)2*BB*KK*NN*4);           // 32*SSTRIDE_W ints
  // total ws use: 256 + 2*294912 + 32*9224*4 = ~1.7 MB

  k_prob<<<(BB*NN+TPB-1)/TPB,TPB,0,stream>>>(preds,probf);
  k_structure<<<32,TPB,0,stream>>>(lowf,hf1,hf2,hf3,sbase);
  k_filter0<<<BB,TPB,0,stream>>>(probf,sbase,AS);
  k_filter123<<<3*BB,TPB,0,stream>>>(AS,probf,rois,sbase,partials);
  k_final<<<1,TPB,0,stream>>>(rois,partials,wt,out);
}

// Round 2
// 848.294 us; speedup vs baseline: 1.7844x; 1.7844x over previous
//
#include <hip/hip_runtime.h>
#include <math.h>

// ---------------------------------------------------------------------------
// TreeEnergyLoss on MI355X.
// softmax -> [k_edges: parallel chunked f64 edge distances via LDS-upsampled
// embeddings] -> [k_structure2: chunk-sum (fixed order) + Boruvka MST under
// strict (dist,edge-idx) order == reference's stable Kruskal + frontier BFS]
// -> two-pass tree filter -> ROI-masked L1 loss.
// ---------------------------------------------------------------------------

#define HH 48
#define WW 48
#define NN (HH*WW)          // 2304 nodes
#define EHH (HH*(WW-1))     // 2256 horizontal edges
#define EEE (2*EHH)         // 4512 edges
#define BB 8
#define KK 4
#define TPB 256
#define NE_PT ((EEE+TPB-1)/TPB)   // 18 edges per thread

// per-problem structure record in ws (ints): parent | wgt | order | levelStart | depth
#define SSTRIDE_W (4*NN+8)
#define P_OFF 0
#define W_OFF NN
#define O_OFF (2*NN)
#define L_OFF (3*NN)
#define D_OFF (4*NN+2)

struct Tap { int o00,o01,o10,o11; float w00,w01,w10,w11; };

__device__ __forceinline__ Tap mk_tap(int r,int c,int sh,int sw){
  float sy=(float)sh/48.0f, sx=(float)sw/48.0f;          // exact (pow2 ratios)
  float ys=fmaxf(((float)r+0.5f)*sy-0.5f,0.0f);
  float xs=fmaxf(((float)c+0.5f)*sx-0.5f,0.0f);
  int y0=(int)ys; if(y0>sh-1) y0=sh-1;
  int x0=(int)xs; if(x0>sw-1) x0=sw-1;
  int y1=y0+1; if(y1>sh-1) y1=sh-1;
  int x1=x0+1; if(x1>sw-1) x1=sw-1;
  float wy=ys-(float)y0, wx=xs-(float)x0;
  Tap t;
  t.o00=y0*sw+x0; t.o01=y0*sw+x1; t.o10=y1*sw+x0; t.o11=y1*sw+x1;
  t.w00=(1.0f-wy)*(1.0f-wx); t.w01=(1.0f-wy)*wx;
  t.w10=wy*(1.0f-wx);        t.w11=wy*wx;
  return t;
}

__device__ __forceinline__ float tap_val(const float* __restrict__ p, const Tap& t){
  return t.w00*p[t.o00]+t.w01*p[t.o01]+t.w10*p[t.o10]+t.w11*p[t.o11];
}

// numpy edge order: horizontal (row-major) first, then vertical.
__device__ __forceinline__ void edge_uv(int e,int& u,int& v){
  if(e<EHH){ int r=e/(WW-1); int c=e-r*(WW-1); u=r*WW+c; v=u+1; }
  else     { int t=e-EHH; u=t; v=t+WW; }
}

__device__ __forceinline__ void pick_src(int f, const float* lowf, const float* hf1,
                                         const float* hf2, const float* hf3,
                                         const float*& src, int& sh, int& C){
  if(f==0){src=lowf; sh=192; C=3;}
  else if(f==1){src=hf1; sh=24; C=512;}
  else if(f==2){src=hf2; sh=12; C=512;}
  else        {src=hf3; sh=6;  C=512;}
}

// ---------------------------------------------------------------------------
__global__ __launch_bounds__(TPB) void k_prob(const float* __restrict__ preds,
                                              float* __restrict__ probf){
  int t=blockIdx.x*TPB+threadIdx.x;
  if(t>=BB*NN) return;
  int b=t/NN, i=t-b*NN;
  const float* p=preds+(size_t)b*KK*NN+i;
  float x0=p[0],x1=p[NN],x2=p[2*NN],x3=p[3*NN];
  float mx=fmaxf(fmaxf(x0,x1),fmaxf(x2,x3));
  float e0=expf(x0-mx),e1=expf(x1-mx),e2=expf(x2-mx),e3=expf(x3-mx);
  float s=((e0+e1)+(e2+e3));
  float* q=probf+(size_t)b*KK*NN+i;
  q[0]=e0/s; q[NN]=e1/s; q[2*NN]=e2/s; q[3*NN]=e3/s;
}

// ---------------------------------------------------------------------------
// Parallel edge-distance partials.  One block = (problem, channel-chunk).
// Upsamples 8 channels at a time into LDS [c][node], then accumulates
// per-edge f64 partial sums in registers (fixed channel order -> ties that
// are structurally exact stay exact across chunking).
__global__ __launch_bounds__(TPB) void k_edges(
  const float* __restrict__ lowf, const float* __restrict__ hf1,
  const float* __restrict__ hf2, const float* __restrict__ hf3,
  double* __restrict__ pd, int nchunk)
{
  __shared__ float up[8*NN];   // 73728 B
  const int tid=threadIdx.x;
  int pidx, chunk;
  if(blockIdx.x<8){ pidx=blockIdx.x; chunk=0; }
  else { int t=blockIdx.x-8; pidx=8+t/nchunk; chunk=t%nchunk; }
  const int f=pidx>>3, b=pidx&7;
  const float* src; int sh,C;
  pick_src(f,lowf,hf1,hf2,hf3,src,sh,C);
  const int shw=sh*sh;
  const float* srcb=src+(size_t)b*C*shw;
  const int cpc=(f==0)?3:(512/nchunk);
  const int c_begin=chunk*cpc;
  const int c_end=(c_begin+cpc<C)?(c_begin+cpc):C;

  double acc[NE_PT];
  #pragma unroll
  for(int j=0;j<NE_PT;j++) acc[j]=0.0;

  for(int c0=c_begin;c0<c_end;c0+=8){
    const int nc=(c_end-c0<8)?(c_end-c0):8;
    __syncthreads();               // protect previous sub-stage reads
    for(int i=tid;i<NN;i+=TPB){
      Tap t=mk_tap(i/WW,i-(i/WW)*WW,sh,sh);
      const float* pl=srcb+(size_t)c0*shw;
      for(int c=0;c<nc;c++) up[c*NN+i]=tap_val(pl+(size_t)c*shw,t);
    }
    __syncthreads();
    #pragma unroll
    for(int j=0;j<NE_PT;j++){
      int e=tid+j*TPB;
      if(e<EEE){
        int u,v; edge_uv(e,u,v);
        double s=acc[j];
        for(int c=0;c<nc;c++){
          double d=(double)up[c*NN+u]-(double)up[c*NN+v];
          s=fma(d,d,s);
        }
        acc[j]=s;
      }
    }
  }
  #pragma unroll
  for(int j=0;j<NE_PT;j++){
    int e=tid+j*TPB;
    if(e<EEE) pd[((size_t)pidx*nchunk+chunk)*EEE+e]=acc[j];
  }
}

// ---------------------------------------------------------------------------
// One workgroup per (forest,batch): sum chunk partials (fixed order), Boruvka
// MST, frontier BFS (emits order[] + levelStart[] directly), wgt.
__global__ __launch_bounds__(TPB) void k_structure2(
  const double* __restrict__ pd, int nchunk, int* __restrict__ sbase)
{
  __shared__ double dkey[EEE];                  // 36096 B
  __shared__ unsigned long long bestd[NN];      // 18432 B
  __shared__ int comp[NN];
  __shared__ int lnk[NN];
  __shared__ int beste[NN];
  __shared__ int parentN[NN];
  __shared__ int ordS[NN];
  __shared__ int lsS[NN+2];
  __shared__ unsigned char mstf[EEE];
  __shared__ int flags[4];

  const int tid=threadIdx.x;
  const int pidx=blockIdx.x;
  const int f=pidx>>3;
  const float sigma=(f==0)?0.02f:1.0f;

  int* sp=sbase+(size_t)pidx*SSTRIDE_W;
  int* g_parent=sp+P_OFF;
  float* g_wgt=(float*)(sp+W_OFF);
  int* g_order=sp+O_OFF;
  int* g_ls=sp+L_OFF;

  // ---- gather edge distances: fixed chunk order (deterministic) ----
  const int nck=(f==0)?1:nchunk;
  for(int e=tid;e<EEE;e+=TPB){
    const double* p=pd+((size_t)pidx*nchunk)*EEE+e;
    double s=0.0;
    for(int k=0;k<nck;k++) s+=p[(size_t)k*EEE];
    dkey[e]=s;
  }
  for(int i=tid;i<NN;i+=TPB) comp[i]=i;
  for(int e=tid;e<EEE;e+=TPB) mstf[e]=0;
  __syncthreads();

  // ---- Boruvka: unique MST under strict (dist_bits, edge_index) order ----
  for(int round=0;round<24;++round){
    for(int i=tid;i<NN;i+=TPB){ bestd[i]=~0ull; beste[i]=0x7fffffff; lnk[i]=i; }
    __syncthreads();
    for(int e=tid;e<EEE;e+=TPB){
      int u,v; edge_uv(e,u,v);
      int cu=comp[u], cv=comp[v];
      if(cu!=cv){
        unsigned long long db=(unsigned long long)__double_as_longlong(dkey[e]);
        atomicMin(&bestd[cu],db);
        atomicMin(&bestd[cv],db);
      }
    }
    __syncthreads();
    for(int e=tid;e<EEE;e+=TPB){
      int u,v; edge_uv(e,u,v);
      int cu=comp[u], cv=comp[v];
      if(cu!=cv){
        unsigned long long db=(unsigned long long)__double_as_longlong(dkey[e]);
        if(db==bestd[cu]) atomicMin(&beste[cu],e);
        if(db==bestd[cv]) atomicMin(&beste[cv],e);
      }
    }
    __syncthreads();
    // hook (mutual pair resolved toward smaller id; mutual => SAME edge since order strict)
    for(int i=tid;i<NN;i+=TPB){
      if(comp[i]==i && beste[i]!=0x7fffffff){
        int e=beste[i]; int u,v; edge_uv(e,u,v);
        int cu=comp[u], cv=comp[v];
        int other=(cu==i)?cv:cu;
        bool mutual=(beste[other]==e);
        if(!mutual || other<i){ lnk[i]=other; mstf[e]=1; }
      }
    }
    __syncthreads();
    // pointer jumping to full compression
    for(;;){
      if(tid==0) flags[0]=0;
      __syncthreads();
      for(int i=tid;i<NN;i+=TPB){
        int a=lnk[i]; int a2=lnk[a];
        if(a!=a2){ lnk[i]=a2; flags[0]=1; }
      }
      __syncthreads();
      int done=flags[0];
      __syncthreads();
      if(!done) break;
    }
    for(int i=tid;i<NN;i+=TPB) comp[i]=lnk[comp[i]];
    __syncthreads();
    if(tid==0) flags[1]=0;
    __syncthreads();
    for(int i=tid;i<NN;i+=TPB) if(comp[i]==i) atomicAdd(&flags[1],1);
    __syncthreads();
    int nc=flags[1];
    __syncthreads();
    if(nc<=1) break;
  }

  // ---- frontier BFS from node 0: builds order[] + levelStart[] directly ----
  // (tree => each unvisited node is adjacent to exactly one frontier node: no race)
  for(int i=tid;i<NN;i+=TPB) lnk[i]=0;          // lnk reused as visited
  __syncthreads();
  if(tid==0){ lnk[0]=1; parentN[0]=0; ordS[0]=0; lsS[0]=0; lsS[1]=1; flags[3]=1; }
  __syncthreads();
  int depth=0;
  for(int l=0;;++l){
    int s=lsS[l], e2=lsS[l+1];
    for(int k=s+tid;k<e2;k+=TPB){
      int i=ordS[k];
      int r=i/WW, c=i-r*WW;
      if(c>0    && mstf[r*(WW-1)+c-1]   && !lnk[i-1]) { lnk[i-1]=1;  parentN[i-1]=i;  int p2=atomicAdd(&flags[3],1); ordS[p2]=i-1; }
      if(c<WW-1 && mstf[r*(WW-1)+c]     && !lnk[i+1]) { lnk[i+1]=1;  parentN[i+1]=i;  int p2=atomicAdd(&flags[3],1); ordS[p2]=i+1; }
      if(r>0    && mstf[EHH+(r-1)*WW+c] && !lnk[i-WW]){ lnk[i-WW]=1; parentN[i-WW]=i; int p2=atomicAdd(&flags[3],1); ordS[p2]=i-WW; }
      if(r<HH-1 && mstf[EHH+r*WW+c]     && !lnk[i+WW]){ lnk[i+WW]=1; parentN[i+WW]=i; int p2=atomicAdd(&flags[3],1); ordS[p2]=i+WW; }
    }
    __syncthreads();
    int tail=flags[3];
    if(tid==0) lsS[l+2]=tail;
    __syncthreads();
    if(tail==lsS[l+1]){ depth=l; break; }
  }

  // ---- wgt[i] = exp(-dist(i,parent)/sigma) ----
  for(int i=tid;i<NN;i+=TPB){
    int p=parentN[i];
    int r=i/WW, c=i-r*WW;
    int e=-1;
    if(p==i+1)      e=r*(WW-1)+c;
    else if(p==i-1) e=r*(WW-1)+(c-1);
    else if(p==i+WW)e=EHH+i;
    else if(p==i-WW)e=EHH+p;
    g_wgt[i]=(e<0)?1.0f:expf(-(float)dkey[e]/sigma);
    g_parent[i]=p;
    g_order[i]=ordS[i];
  }
  for(int i=tid;i<depth+2;i+=TPB) g_ls[i]=lsS[i];
  if(tid==0) sp[D_OFF]=depth;
}

// ---------------------------------------------------------------------------
// Tree filter, forest 0 (input: softmax probs; output: AS).  In-place LDS A.
__global__ __launch_bounds__(TPB) void k_filter0(
  const float* __restrict__ probf, const int* __restrict__ sbase,
  float* __restrict__ AS)
{
  __shared__ float A[(KK+1)*NN];
  __shared__ float wgtS[NN];
  __shared__ int parS[NN];
  __shared__ int ordS[NN];
  __shared__ int lsS[NN+2];
  const int tid=threadIdx.x;
  const int b=blockIdx.x;
  const int* sp=sbase+(size_t)b*SSTRIDE_W;
  const float* g_wgt=(const float*)(sp+W_OFF);
  const int D=sp[D_OFF];
  for(int t=tid;t<(KK+1)*NN;t+=TPB) A[t]=(t<KK*NN)? probf[(size_t)b*KK*NN+t] : 1.0f;
  for(int i=tid;i<NN;i+=TPB){ wgtS[i]=g_wgt[i]; parS[i]=sp[P_OFF+i]; ordS[i]=sp[O_OFF+i]; }
  for(int i=tid;i<D+2;i+=TPB) lsS[i]=sp[L_OFF+i];
  __syncthreads();
  for(int l=D;l>=1;--l){
    int s=lsS[l], e2=lsS[l+1];
    for(int k=s+tid;k<e2;k+=TPB){
      int i=ordS[k]; int p=parS[i]; float w=wgtS[i];
      #pragma unroll
      for(int c=0;c<=KK;c++) atomicAdd(&A[c*NN+p], w*A[c*NN+i]);
    }
    __syncthreads();
  }
  for(int l=1;l<=D;++l){
    int s=lsS[l], e2=lsS[l+1];
    for(int k=s+tid;k<e2;k+=TPB){
      int i=ordS[k]; int p=parS[i]; float w=wgtS[i];
      #pragma unroll
      for(int c=0;c<=KK;c++){
        float a=A[c*NN+i];
        A[c*NN+i]=a+w*(A[c*NN+p]-w*a);
      }
    }
    __syncthreads();
  }
  for(int t=tid;t<KK*NN;t+=TPB){
    int c=t/NN, i=t-c*NN;
    AS[(size_t)b*KK*NN+t]=A[c*NN+i]/A[KK*NN+i];
  }
}

// ---------------------------------------------------------------------------
// Tree filter, forests 1..3 (input: AS) + ROI-masked L1 partial loss.
__global__ __launch_bounds__(TPB) void k_filter123(
  const float* __restrict__ AS, const float* __restrict__ probf,
  const float* __restrict__ rois, const int* __restrict__ sbase,
  float* __restrict__ partials)
{
  __shared__ float A[(KK+1)*NN];
  __shared__ float wgtS[NN];
  __shared__ int parS[NN];
  __shared__ int ordS[NN];
  __shared__ int lsS[NN+2];
  __shared__ float red[TPB];
  const int tid=threadIdx.x;
  const int fm1=blockIdx.x/BB, b=blockIdx.x%BB;
  const int pidx=(fm1+1)*BB+b;
  const int* sp=sbase+(size_t)pidx*SSTRIDE_W;
  const float* g_wgt=(const float*)(sp+W_OFF);
  const int D=sp[D_OFF];
  for(int t=tid;t<(KK+1)*NN;t+=TPB) A[t]=(t<KK*NN)? AS[(size_t)b*KK*NN+t] : 1.0f;
  for(int i=tid;i<NN;i+=TPB){ wgtS[i]=g_wgt[i]; parS[i]=sp[P_OFF+i]; ordS[i]=sp[O_OFF+i]; }
  for(int i=tid;i<D+2;i+=TPB) lsS[i]=sp[L_OFF+i];
  __syncthreads();
  for(int l=D;l>=1;--l){
    int s=lsS[l], e2=lsS[l+1];
    for(int k=s+tid;k<e2;k+=TPB){
      int i=ordS[k]; int p=parS[i]; float w=wgtS[i];
      #pragma unroll
      for(int c=0;c<=KK;c++) atomicAdd(&A[c*NN+p], w*A[c*NN+i]);
    }
    __syncthreads();
  }
  for(int l=1;l<=D;++l){
    int s=lsS[l], e2=lsS[l+1];
    for(int k=s+tid;k<e2;k+=TPB){
      int i=ordS[k]; int p=parS[i]; float w=wgtS[i];
      #pragma unroll
      for(int c=0;c<=KK;c++){
        float a=A[c*NN+i];
        A[c*NN+i]=a+w*(A[c*NN+p]-w*a);
      }
    }
    __syncthreads();
  }
  float part=0.0f;
  for(int i=tid;i<NN;i+=TPB){
    int r=i/WW, c2=i-r*WW;
    float roi=rois[(size_t)b*(192*192)+(4*r)*192+(4*c2)];
    float den=A[KK*NN+i];
    float s=0.0f;
    #pragma unroll
    for(int c=0;c<KK;c++){
      float ask=A[c*NN+i]/den;
      s+=fabsf(probf[(size_t)b*KK*NN+c*NN+i]-ask);
    }
    part+=roi*s;
  }
  red[tid]=part; __syncthreads();
  for(int s2=TPB/2;s2>0;s2>>=1){ if(tid<s2) red[tid]+=red[tid+s2]; __syncthreads(); }
  if(tid==0) partials[blockIdx.x]=red[0];
}

// ---------------------------------------------------------------------------
__global__ __launch_bounds__(TPB) void k_final(const float* __restrict__ rois,
    const float* __restrict__ partials, const float* __restrict__ wt,
    float* __restrict__ out)
{
  __shared__ float red[TPB];
  const int tid=threadIdx.x;
  float n=0.0f;
  for(int t=tid;t<BB*NN;t+=TPB){
    int b=t/NN, i=t-b*NN; int r=i/WW, c=i-r*WW;
    n += rois[(size_t)b*(192*192)+(4*r)*192+(4*c)];
  }
  red[tid]=n; __syncthreads();
  for(int s=TPB/2;s>0;s>>=1){ if(tid<s) red[tid]+=red[tid+s]; __syncthreads(); }
  if(tid==0){
    float loss=0.0f;
    for(int j=0;j<3*BB;j++) loss+=partials[j];
    float N=red[0];
    out[0]=wt[0]*((N>0.0f)?(loss/N):loss);
  }
}

// ---------------------------------------------------------------------------
extern "C" void kernel_launch(void* const* d_in, const int* in_sizes, int n_in,
                              void* d_out, int out_size, void* d_ws, size_t ws_size,
                              hipStream_t stream) {
  (void)in_sizes; (void)n_in; (void)out_size;
  const float* preds=(const float*)d_in[0];
  const float* lowf =(const float*)d_in[1];
  const float* hf1  =(const float*)d_in[2];
  const float* hf2  =(const float*)d_in[3];
  const float* hf3  =(const float*)d_in[4];
  const float* rois =(const float*)d_in[5];
  const float* wt   =(const float*)d_in[6];
  float* out=(float*)d_out;

  char* ws=(char*)d_ws;
  float* partials=(float*)ws;                                   // 24 floats
  float* probf=(float*)(ws+256);                                // B*K*NN
  float* AS   =(float*)(ws+256+(size_t)BB*KK*NN*4);             // B*K*NN
  int*   sbase=(int*)  (ws+256+(size_t)2*BB*KK*NN*4);           // 32*SSTRIDE_W ints
  size_t pd_off=256+(size_t)2*BB*KK*NN*4+(size_t)32*SSTRIDE_W*4; // = 1,770,752 (8-aligned)
  double* pd=(double*)(ws+pd_off);

  // pick the largest channel-chunk count whose partial buffer fits ws
  int nchunk=16;
  while(nchunk>1 && pd_off+(size_t)32*nchunk*EEE*8>ws_size) nchunk>>=1;

  k_prob<<<(BB*NN+TPB-1)/TPB,TPB,0,stream>>>(preds,probf);
  k_edges<<<8+24*nchunk,TPB,0,stream>>>(lowf,hf1,hf2,hf3,pd,nchunk);
  k_structure2<<<32,TPB,0,stream>>>(pd,nchunk,sbase);
  k_filter0<<<BB,TPB,0,stream>>>(probf,sbase,AS);
  k_filter123<<<3*BB,TPB,0,stream>>>(AS,probf,rois,sbase,partials);
  k_final<<<1,TPB,0,stream>>>(rois,partials,wt,out);
}